// Round 13
// baseline (1168.652 us; speedup 1.0000x reference)
//
#include <hip/hip_runtime.h>
#include <math.h>

#define BN 64
#define KIN 1024
#define DOUT 512
#define NN 2048
#define TBLK 128
#define NBLK 16

__device__ __forceinline__ float softplus_f(float x) {
  float e = __expf(-fabsf(x));
  return fmaxf(x, 0.f) + __logf(1.f + e);
}
__device__ __forceinline__ float apply_nl(int id, float v) {
  switch (id) {
    case 0: return fmaxf(v, 0.f);
    case 1: { float e = __expf(2.f * v); return fmaf(-2.f, __builtin_amdgcn_rcpf(e + 1.f), 1.f); }
    case 2: return v >= 0.f ? v : 0.01f * v;
    case 3: return v;
    case 4: return __sinf(v);
    case 5: return softplus_f(v);
    default: return v - softplus_f(v);  // -softplus(-v)
  }
}

// Pipelined branchless nl: candidates computed early, select is a cndmask tree.
__device__ __forceinline__ void nl_cand(float v, float& mx, float& th, float& lk,
                                        float& sn, float& sp, float& sm) {
  mx = fmaxf(v, 0.f);
  lk = fmaf(fminf(v, 0.f), 0.01f, mx);
  float e = __expf(-fabsf(v));
  float e2 = e * e;
  float l1 = __logf(1.f + e);
  sp = mx + l1;
  sm = v - sp;
  th = __builtin_copysignf((1.f - e2) * __builtin_amdgcn_rcpf(1.f + e2), v);
  sn = __sinf(v);
}
__device__ __forceinline__ float nl_sel(int id, float v, float mx, float th, float lk,
                                        float sn, float sp, float sm) {
  float r = v;
  r = (id == 0) ? mx : r;
  r = (id == 1) ? th : r;
  r = (id == 2) ? lk : r;
  r = (id == 4) ? sn : r;
  r = (id == 5) ? sp : r;
  r = (id == 6) ? sm : r;
  return r;
}

// element (m-row, l-col) of per-sub triangle regs tw[16] (float4 pairs per row)
#define TWEL(tw, m, l) (((l) & 3) == 0 ? tw[(m)*2 + ((l) >> 2)].x : \
                        ((l) & 3) == 1 ? tw[(m)*2 + ((l) >> 2)].y : \
                        ((l) & 3) == 2 ? tw[(m)*2 + ((l) >> 2)].z : tw[(m)*2 + ((l) >> 2)].w)

// packed-id extraction (jj compile-time after unroll)
#define ID_AT(idp, jj) ((int)((idp[(jj) >> 2] >> (((jj) & 3) * 8)) & 0xFFu))

// ---------------- adj dtype detection (parallel) ----------------
__global__ void detect_adj(const unsigned int* __restrict__ a, int* __restrict__ flags) {
  int idx = blockIdx.x * 256 + threadIdx.x;  // 16384 dwords = first 64 KiB
  unsigned int v = a[idx];
  bool bad = ((v & 0xFFu) > 1u) || (((v >> 8) & 0xFFu) > 1u) ||
             (((v >> 16) & 0xFFu) > 1u) || ((v >> 24) > 1u);
  bool off = (v & 0xFFFFFF00u) != 0u;
  if (__any(bad) && (threadIdx.x & 63) == 0) atomicOr(&flags[0], 1);
  if (__any(off) && (threadIdx.x & 63) == 0) atomicOr(&flags[1], 1);
}

__global__ void normalize_adj(const unsigned char* __restrict__ a,
                              const int* __restrict__ flags,
                              unsigned char* __restrict__ out) {
  size_t i = (size_t)blockIdx.x * blockDim.x + threadIdx.x;
  int mode = flags[0] ? 2 : (flags[1] ? 1 : 0);
  unsigned char r;
  if (mode == 1)      r = (a[i] != 0);
  else if (mode == 0) r = (((const int*)a)[i] != 0);
  else                r = (((const float*)a)[i] != 0.f);
  out[i] = r;
}

// ---------------- X transpose ----------------
__global__ void transpose_x(const float* __restrict__ X, float* __restrict__ XT) {
  int g = blockIdx.x * blockDim.x + threadIdx.x;
  int k = g >> 6, b = g & 63;
  XT[g] = X[(size_t)b * KIN + k];
}

// ---------------- pack aligned in-block triangles ----------------
__global__ __launch_bounds__(256) void pack_wmid(const float* __restrict__ Wmid,
                                                 const unsigned char* __restrict__ adjN,
                                                 float* __restrict__ wpack) {
  int g = blockIdx.x * 256 + threadIdx.x;  // 65536 float4s
  int i = g >> 12;
  int rem = g & 4095;
  int j = rem >> 5;
  int q4 = (rem & 31) * 4;
  int n0 = 1 + i * TBLK;
  int size = NN - 1 - n0;
  if (size > TBLK) size = TBLK;
  float w[4];
#pragma unroll
  for (int e = 0; e < 4; ++e) {
    int q = q4 + e;
    float v = 0.f;
    if (q > j && j < size && q < size) {
      size_t idx = (size_t)(n0 + j) * NN + (size_t)(n0 + q);
      v = Wmid[idx] * (float)adjN[idx];
    }
    w[e] = v;
  }
  *(float4*)(wpack + (size_t)g * 4) = make_float4(w[0], w[1], w[2], w[3]);
}

// ---------------- unified partial GEMM ----------------
template <int MODE>
__global__ __launch_bounds__(256) void gemm_partial(
    const float* __restrict__ AT, const float* __restrict__ W,
    const unsigned char* __restrict__ adj, float* __restrict__ accT,
    int ldw, int col0, int ncols, int kPerChunk, int nColTiles)
{
  const int ct = blockIdx.x % nColTiles;
  const int kc = blockIdx.x / nColTiles;
  const int c0 = ct * 64;
  const int k0 = kc * kPerChunk;
  const int t = threadIdx.x;
  const int tb = t >> 4;
  const int tc = t & 15;

  __shared__ __align__(16) float At[16][64];
  __shared__ __align__(16) float Wt[16][64];

  float acc[4][4] = {};
  const int sk = t >> 4;
  const int sq = t & 15;

  for (int ks = k0; ks < k0 + kPerChunk; ks += 16) {
    const float4 av = *(const float4*)(AT + (size_t)(ks + sk) * 64 + sq * 4);
    *(float4*)(&At[sk][sq * 4]) = av;
    {
      const float* wrow = W + (size_t)(ks + sk) * ldw + col0;
      float w[4];
      float rowmask = 1.f;
      if (MODE == 2) rowmask = (float)adj[(size_t)(ks + sk) * NN + (NN - 1)];
#pragma unroll
      for (int e = 0; e < 4; ++e) {
        int cl = c0 + sq * 4 + e;
        float wv = 0.f;
        if (cl < ncols) {
          wv = wrow[cl];
          if (MODE == 1) wv *= (float)adj[(size_t)(ks + sk) * NN + col0 + cl];
          if (MODE == 2) wv *= rowmask;
        }
        w[e] = wv;
      }
      *(float4*)(&Wt[sk][sq * 4]) = make_float4(w[0], w[1], w[2], w[3]);
    }
    __syncthreads();
#pragma unroll
    for (int kk = 0; kk < 16; ++kk) {
      float a4[4], w4[4];
#pragma unroll
      for (int e = 0; e < 4; ++e) a4[e] = At[kk][tb * 4 + e];
#pragma unroll
      for (int e = 0; e < 4; ++e) w4[e] = Wt[kk][tc * 4 + e];
#pragma unroll
      for (int i = 0; i < 4; ++i)
#pragma unroll
        for (int j = 0; j < 4; ++j) acc[i][j] = fmaf(a4[i], w4[j], acc[i][j]);
    }
    __syncthreads();
  }

#pragma unroll
  for (int j = 0; j < 4; ++j) {
    int cl = c0 + tc * 4 + j;
    if (cl < ncols) {
      float* dst = accT + (size_t)(col0 + cl) * 64 + tb * 4;
#pragma unroll
      for (int i = 0; i < 4; ++i) atomicAdd(dst + i, acc[i][j]);
    }
  }
}

// ---------------- init finish ----------------
__global__ void init_finish(const float* __restrict__ out0accT, const float* __restrict__ b0,
                            const unsigned char* __restrict__ adjN, const int* __restrict__ nl_idx,
                            float* __restrict__ curT) {
  int g = blockIdx.x * blockDim.x + threadIdx.x;
  int n = g >> 6;
  float v = out0accT[g] + b0[n];
  v = apply_nl(nl_idx[0], v);
  curT[g] = adjN[n] ? v : 0.f;
}

// ---------------- fused solve v6: fence-free handoff, per-step delta export ------
__global__ __launch_bounds__(256, 1) void fused_solve(
    const float* __restrict__ wpack, const float* __restrict__ Wmid,
    const unsigned char* __restrict__ adjN, const int* __restrict__ nlidx,
    const float* __restrict__ bmid, const float* __restrict__ Cbase,
    float* __restrict__ curT, float* __restrict__ deltaG, int* chunkDone)
{
  __shared__ __align__(16) unsigned char smem[132096];
  float (*wmS)[TBLK]     = (float(*)[TBLK])(smem);           // 64 KiB triangle
  float (*wpr)[TBLK]     = (float(*)[TBLK])(smem + 65536);   // 64 KiB cross-pair weights
  float (*deltaFull)[64] = (float(*)[64])(smem + 65536);     // 32 KiB (aliases wpr post-apply)
  int* sfl               = (int*)(smem + 131584);

  const int bi = blockIdx.x;
  const int n0 = 1 + bi * TBLK;
  int size = NN - 1 - n0;
  if (size > TBLK) size = TBLK;
  const int tid = threadIdx.x;
  const int wv = tid >> 6;
  const int b = tid & 63;
  const int qbase = wv * 32;

  // ---- stage triangle (two halves to limit transient regs) ----
  {
    const float4* src = (const float4*)(wpack + (size_t)bi * TBLK * TBLK);
    float4 s0[8];
#pragma unroll
    for (int it = 0; it < 8; ++it) s0[it] = src[it * 256 + tid];
#pragma unroll
    for (int it = 0; it < 8; ++it) ((float4*)&wmS[0][0])[it * 256 + tid] = s0[it];
#pragma unroll
    for (int it = 0; it < 8; ++it) s0[it] = src[(8 + it) * 256 + tid];
#pragma unroll
    for (int it = 0; it < 8; ++it) ((float4*)&wmS[0][0])[(8 + it) * 256 + tid] = s0[it];
  }

  // ---- this wave's own-chunk nl ids, packed 4-per-dword (8 VGPRs) ----
  unsigned idp[8];
#pragma unroll
  for (int g = 0; g < 8; ++g) {
    unsigned v = 0;
#pragma unroll
    for (int e = 0; e < 4; ++e) {
      int q = qbase + g * 4 + e;
      int idq = (q < size) ? nlidx[n0 + q] : 3;
      v |= ((unsigned)idq & 0xFFu) << (e * 8);
    }
    idp[g] = v;
  }

  // ---- val (Cbase + bias) and iv (init state) in registers ----
  float val[32], iv[32];
#pragma unroll
  for (int l = 0; l < 32; ++l) {
    int q = qbase + l, n = n0 + q;
    bool ok = q < size;
    val[l] = ok ? (Cbase[(size_t)n * 64 + b] + bmid[n]) : 0.f;
    iv[l] = ok ? curT[(size_t)n * 64 + b] : 0.f;
  }
  __syncthreads();

  // ---- incremental applies, chunk-granular; relaxed agent loads (no fences) ----
#pragma unroll 1
  for (int p = 0; p < bi; ++p) {
    // prestage masked cross-weights for pair (p -> bi)
    {
      const size_t rowg0 = (size_t)(1 + p * TBLK);
#pragma unroll 1
      for (int it = 0; it < 16; ++it) {
        int idx = it * 256 + tid;
        int r = idx >> 5, c4 = (idx & 31) * 4;
        const float* wrow = Wmid + (rowg0 + r) * NN + n0;
        const unsigned char* arow = adjN + (rowg0 + r) * NN + n0;
        float w[4];
#pragma unroll
        for (int e = 0; e < 4; ++e) {
          int cl = c4 + e;
          w[e] = (cl < size && arow[cl]) ? wrow[cl] : 0.f;
        }
        *(float4*)(&wpr[r][c4]) = make_float4(w[0], w[1], w[2], w[3]);
      }
    }
    __syncthreads();  // wpr staged

#pragma unroll 1
    for (int c2 = 0; c2 < 4; ++c2) {
      // wait for producer p's chunk c2
      {
        int done = 0, cnt = 0;
        while (!done && cnt < 4000000) {
          if (tid == 0) *sfl = atomicAdd(&chunkDone[p * 4 + c2], 0);
          __syncthreads();
          done = *sfl;
          __syncthreads();
          ++cnt;
          if (!done) __builtin_amdgcn_s_sleep(2);
        }
      }
      // relaxed agent-scope loads bypass L1/local-L2: no acquire fence needed
      float* dsrc = (float*)(deltaG + ((size_t)p * TBLK + c2 * 32) * 64 + b);
#pragma unroll
      for (int r = 0; r < 32; ++r) {
        const float d = __hip_atomic_load(&dsrc[(size_t)r * 64],
                                          __ATOMIC_RELAXED, __HIP_MEMORY_SCOPE_AGENT);
        const float4* wr = (const float4*)(&wpr[c2 * 32 + r][qbase]);
#pragma unroll
        for (int g2 = 0; g2 < 8; ++g2) {
          float4 w4 = wr[g2];
          val[g2 * 4 + 0] = fmaf(d, w4.x, val[g2 * 4 + 0]);
          val[g2 * 4 + 1] = fmaf(d, w4.y, val[g2 * 4 + 1]);
          val[g2 * 4 + 2] = fmaf(d, w4.z, val[g2 * 4 + 2]);
          val[g2 * 4 + 3] = fmaf(d, w4.w, val[g2 * 4 + 3]);
        }
      }
    }
    __syncthreads();  // before next p overwrites wpr
  }

  // ---- 4-phase chunked triangular solve; per-step dual delta store ----
  float* dgp = deltaG + (size_t)bi * TBLK * 64 + b;  // own delta column
#pragma unroll 1
  for (int c = 0; c < 4; ++c) {
    if (wv == c) {
      const int jbase = c * 32;
      float cmx, cth, clk, csn, csp, csm;
      nl_cand(val[0], cmx, cth, clk, csn, csp, csm);
      // preload sub-0 triangle
      float4 tw[16];
#pragma unroll
      for (int m = 0; m < 8; ++m) {
        const float4* tr = (const float4*)(&wmS[jbase + m][qbase]);
        tw[m * 2] = tr[0];
        tw[m * 2 + 1] = tr[1];
      }
#pragma unroll
      for (int s = 0; s < 4; ++s) {
        float ds[8];
        // ---- micro-solve: 8 serial steps ----
#pragma unroll
        for (int m = 0; m < 8; ++m) {
          const int jj = s * 8 + m;
          const int j = jbase + jj;
          const int idv = ID_AT(idp, jj);
          float nv = nl_sel(idv, val[jj], cmx, cth, clk, csn, csp, csm);
          float delta = (j < size) ? (nv - iv[jj]) : 0.f;
          ds[m] = delta;
          deltaFull[j][b] = delta;       // LDS (Phase B)
          dgp[(size_t)j * 64] = delta;   // global, fire-and-forget
          if (m < 7) {
            val[s * 8 + m + 1] = fmaf(delta, TWEL(tw, m, m + 1), val[s * 8 + m + 1]);
            nl_cand(val[s * 8 + m + 1], cmx, cth, clk, csn, csp, csm);
#pragma unroll
            for (int l = m + 2; l < 8; ++l)
              val[s * 8 + l] = fmaf(delta, TWEL(tw, m, l), val[s * 8 + l]);
          }
        }
        // ---- prefetch next sub's triangle (independent of batched update) ----
        if (s < 3) {
#pragma unroll
          for (int m = 0; m < 8; ++m) {
            const float4* tr = (const float4*)(&wmS[jbase + (s + 1) * 8 + m][qbase + (s + 1) * 8]);
            tw[m * 2] = tr[0];
            tw[m * 2 + 1] = tr[1];
          }
        }
        // ---- batched rank-8 update of later subs (first group -> cand) ----
        if (s < 3) {
#pragma unroll
          for (int lg = (s + 1) * 2; lg < 8; ++lg) {
#pragma unroll
            for (int m = 0; m < 8; ++m) {
              const float4 w4 = *(const float4*)(&wmS[jbase + s * 8 + m][qbase + lg * 4]);
              val[lg * 4 + 0] = fmaf(ds[m], w4.x, val[lg * 4 + 0]);
              val[lg * 4 + 1] = fmaf(ds[m], w4.y, val[lg * 4 + 1]);
              val[lg * 4 + 2] = fmaf(ds[m], w4.z, val[lg * 4 + 2]);
              val[lg * 4 + 3] = fmaf(ds[m], w4.w, val[lg * 4 + 3]);
            }
            if (lg == (s + 1) * 2)
              nl_cand(val[(s + 1) * 8], cmx, cth, clk, csn, csp, csm);
          }
        }
      }
      // deltas already in HBM-bound queue: drain + release + flag (pre-barrier)
      __threadfence();
      if (b == 0) atomicExch(&chunkDone[bi * 4 + c], 1);
    }
    __syncthreads();  // deltas of chunk c visible in LDS
    if (wv > c) {
      // ---- Phase B: rank-32 update of own slots (full unroll) ----
#pragma unroll
      for (int jj = 0; jj < 32; ++jj) {
        const int j = c * 32 + jj;
        const float delta = deltaFull[j][b];
        const float4* wr = (const float4*)(&wmS[j][qbase]);
#pragma unroll
        for (int g2 = 0; g2 < 8; ++g2) {
          float4 w4 = wr[g2];
          val[g2 * 4 + 0] = fmaf(delta, w4.x, val[g2 * 4 + 0]);
          val[g2 * 4 + 1] = fmaf(delta, w4.y, val[g2 * 4 + 1]);
          val[g2 * 4 + 2] = fmaf(delta, w4.z, val[g2 * 4 + 2]);
          val[g2 * 4 + 3] = fmaf(delta, w4.w, val[g2 * 4 + 3]);
        }
      }
    }
    __syncthreads();
  }

  // ---- final: curT += deltas (curT held iv) ----
  {
    const float4* sdel = (const float4*)&deltaFull[0][0];
    float4* dstC = (float4*)(curT + (size_t)n0 * 64);
#pragma unroll
    for (int it = 0; it < 8; ++it) {
      int v = it * 256 + tid;
      int r = v >> 4;
      if (r < size) {
        float4 d = sdel[v];
        float4 cc = dstC[v];
        dstC[v] = make_float4(cc.x + d.x, cc.y + d.y, cc.z + d.z, cc.w + d.w);
      }
    }
  }
}

// ---------------- final finish ----------------
__global__ void final_finish(const float* __restrict__ outaccT, const float* __restrict__ bout,
                             const int* __restrict__ nlidx, float* __restrict__ out) {
  int g = blockIdx.x * blockDim.x + threadIdx.x;
  int c = g >> 6, b = g & 63;
  float v = outaccT[g] + bout[c];
  v = apply_nl(nlidx[NN - 1], v);
  out[(size_t)b * DOUT + c] = v;
}

// ---------------- state transpose ----------------
__global__ __launch_bounds__(256) void transpose_state(const float* __restrict__ curT,
                                                       float* __restrict__ stateOut) {
  __shared__ float tile[64][65];
  int n0 = blockIdx.x * 64;
  for (int r = 0; r < 16; ++r) {
    int e = r * 256 + threadIdx.x;
    tile[e >> 6][e & 63] = curT[(size_t)(n0 + (e >> 6)) * 64 + (e & 63)];
  }
  __syncthreads();
  for (int r = 0; r < 16; ++r) {
    int e = r * 256 + threadIdx.x;
    int bb = e >> 6, nn2 = e & 63;
    stateOut[(size_t)bb * NN + n0 + nn2] = tile[nn2][bb];
  }
}

extern "C" void kernel_launch(void* const* d_in, const int* in_sizes, int n_in,
                              void* d_out, int out_size, void* d_ws, size_t ws_size,
                              hipStream_t stream) {
  const float* X = (const float*)d_in[0];
  const unsigned char* adj = (const unsigned char*)d_in[1];
  const int* nl_idx = (const int*)d_in[2];
  const float* W0 = (const float*)d_in[3];
  const float* b0 = (const float*)d_in[4];
  const float* W_mid = (const float*)d_in[5];
  const float* b_mid = (const float*)d_in[6];
  const float* W_out = (const float*)d_in[7];
  const float* b_out = (const float*)d_in[8];
  float* out = (float*)d_out;
  float* stateOut = out + BN * DOUT;

  char* ws = (char*)d_ws;
  unsigned char* adjN = (unsigned char*)(ws + 0);       // 4 MiB
  int* flags = (int*)(ws + 4194304);                    // 512 B: [0..1]=detect, [8..71]=chunkDone
  float* XT = (float*)(ws + 4194816);                   // 256 KiB
  float* curT = (float*)(ws + 4456960);                 // 512 KiB
  float* Cbase = (float*)(ws + 4981248);                // 512 KiB (read-only after GEMM)
  float* out0accT = (float*)(ws + 5505536);             // 512 KiB
  float* outaccT = (float*)(ws + 6029824);              // 128 KiB
  float* wpack = (float*)(ws + 6160896);                // 1 MiB
  float* deltaG = (float*)(ws + 7209472);               // 512 KiB -> end 7733760
  int* chunkDone = flags + 8;

  hipMemsetAsync(flags, 0, 512, stream);
  hipMemsetAsync(Cbase, 0, 524288 + 524288 + 131072, stream);

  detect_adj<<<64, 256, 0, stream>>>((const unsigned int*)adj, flags);
  normalize_adj<<<16384, 256, 0, stream>>>(adj, flags, adjN);
  transpose_x<<<256, 256, 0, stream>>>(X, XT);
  pack_wmid<<<256, 256, 0, stream>>>(W_mid, adjN, wpack);

  gemm_partial<0><<<128, 256, 0, stream>>>(XT, W0, adjN, out0accT, NN, 0, NN, 256, 32);
  init_finish<<<512, 256, 0, stream>>>(out0accT, b0, adjN, nl_idx, curT);

  // Cbase: state_0 @ (W_mid * adj) for ALL columns (read-only afterwards)
  gemm_partial<1><<<256, 256, 0, stream>>>(curT, W_mid, adjN, Cbase, NN, 0, NN, 256, 32);

  // entire sequential middle: 16 self-applying solver WGs, per-chunk pipelined
  fused_solve<<<NBLK, 256, 0, stream>>>(wpack, W_mid, adjN, nl_idx, b_mid, Cbase,
                                        curT, deltaG, chunkDone);

  gemm_partial<2><<<64, 256, 0, stream>>>(curT, W_out, adjN, outaccT, DOUT, 0, DOUT, 256, 8);
  final_finish<<<128, 256, 0, stream>>>(outaccT, b_out, nl_idx, out);
  transpose_state<<<32, 256, 0, stream>>>(curT, stateOut);
}

// Round 14
// 989.342 us; speedup vs baseline: 1.1812x; 1.1812x over previous
//
#include <hip/hip_runtime.h>
#include <math.h>

#define BN 64
#define KIN 1024
#define DOUT 512
#define NN 2048
#define TBLK 128
#define NBLK 16

__device__ __forceinline__ float softplus_f(float x) {
  float e = __expf(-fabsf(x));
  return fmaxf(x, 0.f) + __logf(1.f + e);
}
__device__ __forceinline__ float apply_nl(int id, float v) {
  switch (id) {
    case 0: return fmaxf(v, 0.f);
    case 1: { float e = __expf(2.f * v); return fmaf(-2.f, __builtin_amdgcn_rcpf(e + 1.f), 1.f); }
    case 2: return v >= 0.f ? v : 0.01f * v;
    case 3: return v;
    case 4: return __sinf(v);
    case 5: return softplus_f(v);
    default: return v - softplus_f(v);  // -softplus(-v)
  }
}

// Pipelined branchless nl: candidates computed early; select = balanced 3-deep tree.
__device__ __forceinline__ void nl_cand(float v, float& mx, float& th, float& lk,
                                        float& sn, float& sp, float& sm) {
  mx = fmaxf(v, 0.f);
  lk = fmaf(fminf(v, 0.f), 0.01f, mx);
  float e = __expf(-fabsf(v));
  float e2 = e * e;
  float l1 = __logf(1.f + e);
  sp = mx + l1;
  sm = v - sp;
  th = __builtin_copysignf((1.f - e2) * __builtin_amdgcn_rcpf(1.f + e2), v);
  sn = __sinf(v);
}
__device__ __forceinline__ float nl_sel(int id, float v, float mx, float th, float lk,
                                        float sn, float sp, float sm) {
  float a = (id == 0) ? mx : th;   // ids 0,1
  float bq = (id == 2) ? lk : v;   // ids 2,3
  float cq = (id == 4) ? sn : sp;  // ids 4,5
  float ab = (id <= 1) ? a : bq;   // ids 0..3
  float cd = (id <= 5) ? cq : sm;  // ids 4..6
  return (id <= 3) ? ab : cd;      // depth 3
}

// element (m-row, l-col) of per-sub triangle regs tw[16] (float4 pairs per row)
#define TWEL(tw, m, l) (((l) & 3) == 0 ? tw[(m)*2 + ((l) >> 2)].x : \
                        ((l) & 3) == 1 ? tw[(m)*2 + ((l) >> 2)].y : \
                        ((l) & 3) == 2 ? tw[(m)*2 + ((l) >> 2)].z : tw[(m)*2 + ((l) >> 2)].w)

// ---------------- adj dtype detection (parallel) ----------------
__global__ void detect_adj(const unsigned int* __restrict__ a, int* __restrict__ flags) {
  int idx = blockIdx.x * 256 + threadIdx.x;  // 16384 dwords = first 64 KiB
  unsigned int v = a[idx];
  bool bad = ((v & 0xFFu) > 1u) || (((v >> 8) & 0xFFu) > 1u) ||
             (((v >> 16) & 0xFFu) > 1u) || ((v >> 24) > 1u);
  bool off = (v & 0xFFFFFF00u) != 0u;
  if (__any(bad) && (threadIdx.x & 63) == 0) atomicOr(&flags[0], 1);
  if (__any(off) && (threadIdx.x & 63) == 0) atomicOr(&flags[1], 1);
}

__global__ void normalize_adj(const unsigned char* __restrict__ a,
                              const int* __restrict__ flags,
                              unsigned char* __restrict__ out) {
  size_t i = (size_t)blockIdx.x * blockDim.x + threadIdx.x;
  int mode = flags[0] ? 2 : (flags[1] ? 1 : 0);
  unsigned char r;
  if (mode == 1)      r = (a[i] != 0);
  else if (mode == 0) r = (((const int*)a)[i] != 0);
  else                r = (((const float*)a)[i] != 0.f);
  out[i] = r;
}

// ---------------- X transpose ----------------
__global__ void transpose_x(const float* __restrict__ X, float* __restrict__ XT) {
  int g = blockIdx.x * blockDim.x + threadIdx.x;
  int k = g >> 6, b = g & 63;
  XT[g] = X[(size_t)b * KIN + k];
}

// ---------------- pack aligned in-block triangles ----------------
__global__ __launch_bounds__(256) void pack_wmid(const float* __restrict__ Wmid,
                                                 const unsigned char* __restrict__ adjN,
                                                 float* __restrict__ wpack) {
  int g = blockIdx.x * 256 + threadIdx.x;  // 65536 float4s
  int i = g >> 12;
  int rem = g & 4095;
  int j = rem >> 5;
  int q4 = (rem & 31) * 4;
  int n0 = 1 + i * TBLK;
  int size = NN - 1 - n0;
  if (size > TBLK) size = TBLK;
  float w[4];
#pragma unroll
  for (int e = 0; e < 4; ++e) {
    int q = q4 + e;
    float v = 0.f;
    if (q > j && j < size && q < size) {
      size_t idx = (size_t)(n0 + j) * NN + (size_t)(n0 + q);
      v = Wmid[idx] * (float)adjN[idx];
    }
    w[e] = v;
  }
  *(float4*)(wpack + (size_t)g * 4) = make_float4(w[0], w[1], w[2], w[3]);
}

// ---------------- unified partial GEMM ----------------
template <int MODE>
__global__ __launch_bounds__(256) void gemm_partial(
    const float* __restrict__ AT, const float* __restrict__ W,
    const unsigned char* __restrict__ adj, float* __restrict__ accT,
    int ldw, int col0, int ncols, int kPerChunk, int nColTiles)
{
  const int ct = blockIdx.x % nColTiles;
  const int kc = blockIdx.x / nColTiles;
  const int c0 = ct * 64;
  const int k0 = kc * kPerChunk;
  const int t = threadIdx.x;
  const int tb = t >> 4;
  const int tc = t & 15;

  __shared__ __align__(16) float At[16][64];
  __shared__ __align__(16) float Wt[16][64];

  float acc[4][4] = {};
  const int sk = t >> 4;
  const int sq = t & 15;

  for (int ks = k0; ks < k0 + kPerChunk; ks += 16) {
    const float4 av = *(const float4*)(AT + (size_t)(ks + sk) * 64 + sq * 4);
    *(float4*)(&At[sk][sq * 4]) = av;
    {
      const float* wrow = W + (size_t)(ks + sk) * ldw + col0;
      float w[4];
      float rowmask = 1.f;
      if (MODE == 2) rowmask = (float)adj[(size_t)(ks + sk) * NN + (NN - 1)];
#pragma unroll
      for (int e = 0; e < 4; ++e) {
        int cl = c0 + sq * 4 + e;
        float wv = 0.f;
        if (cl < ncols) {
          wv = wrow[cl];
          if (MODE == 1) wv *= (float)adj[(size_t)(ks + sk) * NN + col0 + cl];
          if (MODE == 2) wv *= rowmask;
        }
        w[e] = wv;
      }
      *(float4*)(&Wt[sk][sq * 4]) = make_float4(w[0], w[1], w[2], w[3]);
    }
    __syncthreads();
#pragma unroll
    for (int kk = 0; kk < 16; ++kk) {
      float a4[4], w4[4];
#pragma unroll
      for (int e = 0; e < 4; ++e) a4[e] = At[kk][tb * 4 + e];
#pragma unroll
      for (int e = 0; e < 4; ++e) w4[e] = Wt[kk][tc * 4 + e];
#pragma unroll
      for (int i = 0; i < 4; ++i)
#pragma unroll
        for (int j = 0; j < 4; ++j) acc[i][j] = fmaf(a4[i], w4[j], acc[i][j]);
    }
    __syncthreads();
  }

#pragma unroll
  for (int j = 0; j < 4; ++j) {
    int cl = c0 + tc * 4 + j;
    if (cl < ncols) {
      float* dst = accT + (size_t)(col0 + cl) * 64 + tb * 4;
#pragma unroll
      for (int i = 0; i < 4; ++i) atomicAdd(dst + i, acc[i][j]);
    }
  }
}

// ---------------- init finish ----------------
__global__ void init_finish(const float* __restrict__ out0accT, const float* __restrict__ b0,
                            const unsigned char* __restrict__ adjN, const int* __restrict__ nl_idx,
                            float* __restrict__ curT) {
  int g = blockIdx.x * blockDim.x + threadIdx.x;
  int n = g >> 6;
  float v = out0accT[g] + b0[n];
  v = apply_nl(nl_idx[0], v);
  curT[g] = adjN[n] ? v : 0.f;
}

// ---------------- fused solve v7: R12 base + old-pred fast path + balanced sel ----
__global__ __launch_bounds__(256, 1) void fused_solve(
    const float* __restrict__ wpack, const float* __restrict__ Wmid,
    const unsigned char* __restrict__ adjN, const int* __restrict__ nlidx,
    const float* __restrict__ bmid, const float* __restrict__ Cbase,
    float* __restrict__ curT, float* __restrict__ deltaG, int* chunkDone)
{
  __shared__ __align__(16) unsigned char smem[132096];
  float (*wmS)[TBLK]     = (float(*)[TBLK])(smem);           // 64 KiB triangle
  float (*wpr)[TBLK]     = (float(*)[TBLK])(smem + 65536);   // 64 KiB cross-pair weights
  float (*deltaFull)[64] = (float(*)[64])(smem + 65536);     // 32 KiB (aliases wpr post-apply)
  int* idS               = (int*)(smem + 131072);            // 512 B
  int* sfl               = (int*)(smem + 131584);

  const int bi = blockIdx.x;
  const int n0 = 1 + bi * TBLK;
  int size = NN - 1 - n0;
  if (size > TBLK) size = TBLK;
  const int tid = threadIdx.x;
  const int wv = tid >> 6;
  const int b = tid & 63;
  const int qbase = wv * 32;

  // ---- stage triangle (two halves to limit transient regs) ----
  {
    const float4* src = (const float4*)(wpack + (size_t)bi * TBLK * TBLK);
    float4 s0[8];
#pragma unroll
    for (int it = 0; it < 8; ++it) s0[it] = src[it * 256 + tid];
#pragma unroll
    for (int it = 0; it < 8; ++it) ((float4*)&wmS[0][0])[it * 256 + tid] = s0[it];
#pragma unroll
    for (int it = 0; it < 8; ++it) s0[it] = src[(8 + it) * 256 + tid];
#pragma unroll
    for (int it = 0; it < 8; ++it) ((float4*)&wmS[0][0])[(8 + it) * 256 + tid] = s0[it];
  }
  if (tid < TBLK) idS[tid] = (tid < size) ? nlidx[n0 + tid] : 3;

  // ---- val (Cbase + bias) and iv (init state) in registers ----
  float val[32], iv[32];
#pragma unroll
  for (int l = 0; l < 32; ++l) {
    int q = qbase + l, n = n0 + q;
    bool ok = q < size;
    val[l] = ok ? (Cbase[(size_t)n * 64 + b] + bmid[n]) : 0.f;
    iv[l] = ok ? curT[(size_t)n * 64 + b] : 0.f;
  }
  __syncthreads();

  // ---- incremental applies ----
#pragma unroll 1
  for (int p = 0; p < bi; ++p) {
    // prestage masked cross-weights for pair (p -> bi)
    {
      const size_t rowg0 = (size_t)(1 + p * TBLK);
#pragma unroll 1
      for (int it = 0; it < 16; ++it) {
        int idx = it * 256 + tid;
        int r = idx >> 5, c4 = (idx & 31) * 4;
        const float* wrow = Wmid + (rowg0 + r) * NN + n0;
        const unsigned char* arow = adjN + (rowg0 + r) * NN + n0;
        float w[4];
#pragma unroll
        for (int e = 0; e < 4; ++e) {
          int cl = c4 + e;
          w[e] = (cl < size && arow[cl]) ? wrow[cl] : 0.f;
        }
        *(float4*)(&wpr[r][c4]) = make_float4(w[0], w[1], w[2], w[3]);
      }
    }
    __syncthreads();  // wpr staged

    if (p < bi - 1) {
      // ---- old producer: single wait on last-chunk flag, one acquire, full apply ----
      {
        int done = 0, cnt = 0;
        while (!done && cnt < 4000000) {
          if (tid == 0) *sfl = atomicAdd(&chunkDone[p * 4 + 3], 0);
          __syncthreads();
          done = *sfl;
          __syncthreads();
          ++cnt;
          if (!done) __builtin_amdgcn_s_sleep(2);
        }
      }
      __threadfence();  // acquire all 4 chunks at once
      const float* dsrc = deltaG + (size_t)p * TBLK * 64 + b;
#pragma unroll 8
      for (int r = 0; r < TBLK; ++r) {
        const float d = dsrc[(size_t)r * 64];
        const float4* wr = (const float4*)(&wpr[r][qbase]);
#pragma unroll
        for (int g2 = 0; g2 < 8; ++g2) {
          float4 w4 = wr[g2];
          val[g2 * 4 + 0] = fmaf(d, w4.x, val[g2 * 4 + 0]);
          val[g2 * 4 + 1] = fmaf(d, w4.y, val[g2 * 4 + 1]);
          val[g2 * 4 + 2] = fmaf(d, w4.z, val[g2 * 4 + 2]);
          val[g2 * 4 + 3] = fmaf(d, w4.w, val[g2 * 4 + 3]);
        }
      }
    } else {
      // ---- live producer: per-chunk pipelined (R12 path) ----
#pragma unroll 1
      for (int c2 = 0; c2 < 4; ++c2) {
        {
          int done = 0, cnt = 0;
          while (!done && cnt < 4000000) {
            if (tid == 0) *sfl = atomicAdd(&chunkDone[p * 4 + c2], 0);
            __syncthreads();
            done = *sfl;
            __syncthreads();
            ++cnt;
            if (!done) __builtin_amdgcn_s_sleep(2);
          }
        }
        __threadfence();  // acquire producer's chunk deltas
        const float* dsrc = deltaG + ((size_t)p * TBLK + c2 * 32) * 64 + b;
#pragma unroll
        for (int r = 0; r < 32; ++r) {
          const float d = dsrc[(size_t)r * 64];
          const float4* wr = (const float4*)(&wpr[c2 * 32 + r][qbase]);
#pragma unroll
          for (int g2 = 0; g2 < 8; ++g2) {
            float4 w4 = wr[g2];
            val[g2 * 4 + 0] = fmaf(d, w4.x, val[g2 * 4 + 0]);
            val[g2 * 4 + 1] = fmaf(d, w4.y, val[g2 * 4 + 1]);
            val[g2 * 4 + 2] = fmaf(d, w4.z, val[g2 * 4 + 2]);
            val[g2 * 4 + 3] = fmaf(d, w4.w, val[g2 * 4 + 3]);
          }
        }
      }
    }
    __syncthreads();  // before next p overwrites wpr
  }

  // ---- 4-phase chunked triangular solve; Phase A sub-chunked 8-wide ----
#pragma unroll 1
  for (int c = 0; c < 4; ++c) {
    if (wv == c) {
      const int jbase = c * 32;
      float cmx, cth, clk, csn, csp, csm;
      nl_cand(val[0], cmx, cth, clk, csn, csp, csm);
      int idv = idS[jbase];
#pragma unroll
      for (int s = 0; s < 4; ++s) {
        // preload in-sub 8x8 triangle rows into regs
        float4 tw[16];
#pragma unroll
        for (int m = 0; m < 8; ++m) {
          const float4* tr = (const float4*)(&wmS[jbase + s * 8 + m][qbase + s * 8]);
          tw[m * 2] = tr[0];
          tw[m * 2 + 1] = tr[1];
        }
        float ds[8];
        // ---- micro-solve: 8 serial steps ----
#pragma unroll
        for (int m = 0; m < 8; ++m) {
          const int jj = s * 8 + m;
          const int j = jbase + jj;
          float nv = nl_sel(idv, val[jj], cmx, cth, clk, csn, csp, csm);
          float delta = (j < size) ? (nv - iv[jj]) : 0.f;
          ds[m] = delta;
          deltaFull[j][b] = delta;
          if (jj < 31) idv = idS[jbase + jj + 1];
          if (m < 7) {
            val[s * 8 + m + 1] = fmaf(delta, TWEL(tw, m, m + 1), val[s * 8 + m + 1]);
            nl_cand(val[s * 8 + m + 1], cmx, cth, clk, csn, csp, csm);
#pragma unroll
            for (int l = m + 2; l < 8; ++l)
              val[s * 8 + l] = fmaf(delta, TWEL(tw, m, l), val[s * 8 + l]);
          }
        }
        // ---- batched rank-8 update of later subs (first group -> cand) ----
        if (s < 3) {
#pragma unroll
          for (int lg = (s + 1) * 2; lg < 8; ++lg) {
#pragma unroll
            for (int m = 0; m < 8; ++m) {
              const float4 w4 = *(const float4*)(&wmS[jbase + s * 8 + m][qbase + lg * 4]);
              val[lg * 4 + 0] = fmaf(ds[m], w4.x, val[lg * 4 + 0]);
              val[lg * 4 + 1] = fmaf(ds[m], w4.y, val[lg * 4 + 1]);
              val[lg * 4 + 2] = fmaf(ds[m], w4.z, val[lg * 4 + 2]);
              val[lg * 4 + 3] = fmaf(ds[m], w4.w, val[lg * 4 + 3]);
            }
            if (lg == (s + 1) * 2)
              nl_cand(val[(s + 1) * 8], cmx, cth, clk, csn, csp, csm);
          }
        }
      }
    }
    __syncthreads();  // deltas of chunk c visible in LDS
    if (wv == c) {
      // ---- wave c (idle in Phase B): export chunk deltas + flag ----
      const float4* sdel = (const float4*)(&deltaFull[c * 32][0]);  // 512 float4
      float4* dstD = (float4*)(deltaG + ((size_t)bi * TBLK + c * 32) * 64);
#pragma unroll
      for (int it = 0; it < 8; ++it) dstD[it * 64 + b] = sdel[it * 64 + b];
      __threadfence();  // wave-level vmcnt drain + release
      if (b == 0) atomicExch(&chunkDone[bi * 4 + c], 1);
    } else if (wv > c) {
      // ---- Phase B: rank-32 update of own slots (full unroll) ----
#pragma unroll
      for (int jj = 0; jj < 32; ++jj) {
        const int j = c * 32 + jj;
        const float delta = deltaFull[j][b];
        const float4* wr = (const float4*)(&wmS[j][qbase]);
#pragma unroll
        for (int g2 = 0; g2 < 8; ++g2) {
          float4 w4 = wr[g2];
          val[g2 * 4 + 0] = fmaf(delta, w4.x, val[g2 * 4 + 0]);
          val[g2 * 4 + 1] = fmaf(delta, w4.y, val[g2 * 4 + 1]);
          val[g2 * 4 + 2] = fmaf(delta, w4.z, val[g2 * 4 + 2]);
          val[g2 * 4 + 3] = fmaf(delta, w4.w, val[g2 * 4 + 3]);
        }
      }
    }
    __syncthreads();
  }

  // ---- final: curT += deltas (curT held iv) ----
  {
    const float4* sdel = (const float4*)&deltaFull[0][0];
    float4* dstC = (float4*)(curT + (size_t)n0 * 64);
#pragma unroll
    for (int it = 0; it < 8; ++it) {
      int v = it * 256 + tid;
      int r = v >> 4;
      if (r < size) {
        float4 d = sdel[v];
        float4 cc = dstC[v];
        dstC[v] = make_float4(cc.x + d.x, cc.y + d.y, cc.z + d.z, cc.w + d.w);
      }
    }
  }
}

// ---------------- final finish ----------------
__global__ void final_finish(const float* __restrict__ outaccT, const float* __restrict__ bout,
                             const int* __restrict__ nlidx, float* __restrict__ out) {
  int g = blockIdx.x * blockDim.x + threadIdx.x;
  int c = g >> 6, b = g & 63;
  float v = outaccT[g] + bout[c];
  v = apply_nl(nlidx[NN - 1], v);
  out[(size_t)b * DOUT + c] = v;
}

// ---------------- state transpose ----------------
__global__ __launch_bounds__(256) void transpose_state(const float* __restrict__ curT,
                                                       float* __restrict__ stateOut) {
  __shared__ float tile[64][65];
  int n0 = blockIdx.x * 64;
  for (int r = 0; r < 16; ++r) {
    int e = r * 256 + threadIdx.x;
    tile[e >> 6][e & 63] = curT[(size_t)(n0 + (e >> 6)) * 64 + (e & 63)];
  }
  __syncthreads();
  for (int r = 0; r < 16; ++r) {
    int e = r * 256 + threadIdx.x;
    int bb = e >> 6, nn2 = e & 63;
    stateOut[(size_t)bb * NN + n0 + nn2] = tile[nn2][bb];
  }
}

extern "C" void kernel_launch(void* const* d_in, const int* in_sizes, int n_in,
                              void* d_out, int out_size, void* d_ws, size_t ws_size,
                              hipStream_t stream) {
  const float* X = (const float*)d_in[0];
  const unsigned char* adj = (const unsigned char*)d_in[1];
  const int* nl_idx = (const int*)d_in[2];
  const float* W0 = (const float*)d_in[3];
  const float* b0 = (const float*)d_in[4];
  const float* W_mid = (const float*)d_in[5];
  const float* b_mid = (const float*)d_in[6];
  const float* W_out = (const float*)d_in[7];
  const float* b_out = (const float*)d_in[8];
  float* out = (float*)d_out;
  float* stateOut = out + BN * DOUT;

  char* ws = (char*)d_ws;
  unsigned char* adjN = (unsigned char*)(ws + 0);       // 4 MiB
  int* flags = (int*)(ws + 4194304);                    // 512 B: [0..1]=detect, [8..71]=chunkDone
  float* XT = (float*)(ws + 4194816);                   // 256 KiB
  float* curT = (float*)(ws + 4456960);                 // 512 KiB
  float* Cbase = (float*)(ws + 4981248);                // 512 KiB (read-only after GEMM)
  float* out0accT = (float*)(ws + 5505536);             // 512 KiB
  float* outaccT = (float*)(ws + 6029824);              // 128 KiB
  float* wpack = (float*)(ws + 6160896);                // 1 MiB
  float* deltaG = (float*)(ws + 7209472);               // 512 KiB -> end 7733760
  int* chunkDone = flags + 8;

  hipMemsetAsync(flags, 0, 512, stream);
  hipMemsetAsync(Cbase, 0, 524288 + 524288 + 131072, stream);

  detect_adj<<<64, 256, 0, stream>>>((const unsigned int*)adj, flags);
  normalize_adj<<<16384, 256, 0, stream>>>(adj, flags, adjN);
  transpose_x<<<256, 256, 0, stream>>>(X, XT);
  pack_wmid<<<256, 256, 0, stream>>>(W_mid, adjN, wpack);

  gemm_partial<0><<<128, 256, 0, stream>>>(XT, W0, adjN, out0accT, NN, 0, NN, 256, 32);
  init_finish<<<512, 256, 0, stream>>>(out0accT, b0, adjN, nl_idx, curT);

  // Cbase: state_0 @ (W_mid * adj) for ALL columns (read-only afterwards)
  gemm_partial<1><<<256, 256, 0, stream>>>(curT, W_mid, adjN, Cbase, NN, 0, NN, 256, 32);

  // entire sequential middle: 16 self-applying solver WGs, per-chunk pipelined
  fused_solve<<<NBLK, 256, 0, stream>>>(wpack, W_mid, adjN, nl_idx, b_mid, Cbase,
                                        curT, deltaG, chunkDone);

  gemm_partial<2><<<64, 256, 0, stream>>>(curT, W_out, adjN, outaccT, DOUT, 0, DOUT, 256, 8);
  final_finish<<<128, 256, 0, stream>>>(outaccT, b_out, nl_idx, out);
  transpose_state<<<32, 256, 0, stream>>>(curT, stateOut);
}

// Round 15
// 742.046 us; speedup vs baseline: 1.5749x; 1.3333x over previous
//
#include <hip/hip_runtime.h>
#include <math.h>

#define BN 64
#define KIN 1024
#define DOUT 512
#define NN 2048
#define TBLK 128
#define NBLK 16

__device__ __forceinline__ float softplus_f(float x) {
  float e = __expf(-fabsf(x));
  return fmaxf(x, 0.f) + __logf(1.f + e);
}
__device__ __forceinline__ float apply_nl(int id, float v) {
  switch (id) {
    case 0: return fmaxf(v, 0.f);
    case 1: { float e = __expf(2.f * v); return fmaf(-2.f, __builtin_amdgcn_rcpf(e + 1.f), 1.f); }
    case 2: return v >= 0.f ? v : 0.01f * v;
    case 3: return v;
    case 4: return __sinf(v);
    case 5: return softplus_f(v);
    default: return v - softplus_f(v);  // -softplus(-v)
  }
}

// Prep-only-what's-needed nl (serial-solver path):
// nl_prep computes ONLY the expensive candidate for this node (wave-uniform branch),
// scheduled in the previous step's FMA shadow. nl_fin is a 3-cndmask cheap select.
__device__ __forceinline__ float nl_prep(int id, float v) {
  id = __builtin_amdgcn_readfirstlane(id);
  if (id == 0 || id == 2 || id == 3) return 0.f;  // cheap ids: no prep needed
  if (id == 4) return __sinf(v);
  if (id == 1) {
    float e = __expf(2.f * v);
    return fmaf(-2.f, __builtin_amdgcn_rcpf(e + 1.f), 1.f);
  }
  float sp = softplus_f(v);
  return (id == 5) ? sp : v - sp;  // 5: softplus, 6: softminus
}
__device__ __forceinline__ float nl_fin(int id, float v, float pre) {
  float mx = fmaxf(v, 0.f);
  float r = (id == 2) ? fmaf(fminf(v, 0.f), 0.01f, mx) : pre;
  r = (id == 0) ? mx : r;
  r = (id == 3) ? v : r;
  return r;
}

// element (m-row, l-col) of per-sub triangle regs tw[16] (float4 pairs per row)
#define TWEL(tw, m, l) (((l) & 3) == 0 ? tw[(m)*2 + ((l) >> 2)].x : \
                        ((l) & 3) == 1 ? tw[(m)*2 + ((l) >> 2)].y : \
                        ((l) & 3) == 2 ? tw[(m)*2 + ((l) >> 2)].z : tw[(m)*2 + ((l) >> 2)].w)

// ---------------- adj dtype detection (parallel) ----------------
__global__ void detect_adj(const unsigned int* __restrict__ a, int* __restrict__ flags) {
  int idx = blockIdx.x * 256 + threadIdx.x;  // 16384 dwords = first 64 KiB
  unsigned int v = a[idx];
  bool bad = ((v & 0xFFu) > 1u) || (((v >> 8) & 0xFFu) > 1u) ||
             (((v >> 16) & 0xFFu) > 1u) || ((v >> 24) > 1u);
  bool off = (v & 0xFFFFFF00u) != 0u;
  if (__any(bad) && (threadIdx.x & 63) == 0) atomicOr(&flags[0], 1);
  if (__any(off) && (threadIdx.x & 63) == 0) atomicOr(&flags[1], 1);
}

__global__ void normalize_adj(const unsigned char* __restrict__ a,
                              const int* __restrict__ flags,
                              unsigned char* __restrict__ out) {
  size_t i = (size_t)blockIdx.x * blockDim.x + threadIdx.x;
  int mode = flags[0] ? 2 : (flags[1] ? 1 : 0);
  unsigned char r;
  if (mode == 1)      r = (a[i] != 0);
  else if (mode == 0) r = (((const int*)a)[i] != 0);
  else                r = (((const float*)a)[i] != 0.f);
  out[i] = r;
}

// ---------------- X transpose ----------------
__global__ void transpose_x(const float* __restrict__ X, float* __restrict__ XT) {
  int g = blockIdx.x * blockDim.x + threadIdx.x;
  int k = g >> 6, b = g & 63;
  XT[g] = X[(size_t)b * KIN + k];
}

// ---------------- pack aligned in-block triangles ----------------
__global__ __launch_bounds__(256) void pack_wmid(const float* __restrict__ Wmid,
                                                 const unsigned char* __restrict__ adjN,
                                                 float* __restrict__ wpack) {
  int g = blockIdx.x * 256 + threadIdx.x;  // 65536 float4s
  int i = g >> 12;
  int rem = g & 4095;
  int j = rem >> 5;
  int q4 = (rem & 31) * 4;
  int n0 = 1 + i * TBLK;
  int size = NN - 1 - n0;
  if (size > TBLK) size = TBLK;
  float w[4];
#pragma unroll
  for (int e = 0; e < 4; ++e) {
    int q = q4 + e;
    float v = 0.f;
    if (q > j && j < size && q < size) {
      size_t idx = (size_t)(n0 + j) * NN + (size_t)(n0 + q);
      v = Wmid[idx] * (float)adjN[idx];
    }
    w[e] = v;
  }
  *(float4*)(wpack + (size_t)g * 4) = make_float4(w[0], w[1], w[2], w[3]);
}

// ---------------- unified partial GEMM ----------------
template <int MODE>
__global__ __launch_bounds__(256) void gemm_partial(
    const float* __restrict__ AT, const float* __restrict__ W,
    const unsigned char* __restrict__ adj, float* __restrict__ accT,
    int ldw, int col0, int ncols, int kPerChunk, int nColTiles)
{
  const int ct = blockIdx.x % nColTiles;
  const int kc = blockIdx.x / nColTiles;
  const int c0 = ct * 64;
  const int k0 = kc * kPerChunk;
  const int t = threadIdx.x;
  const int tb = t >> 4;
  const int tc = t & 15;

  __shared__ __align__(16) float At[16][64];
  __shared__ __align__(16) float Wt[16][64];

  float acc[4][4] = {};
  const int sk = t >> 4;
  const int sq = t & 15;

  for (int ks = k0; ks < k0 + kPerChunk; ks += 16) {
    const float4 av = *(const float4*)(AT + (size_t)(ks + sk) * 64 + sq * 4);
    *(float4*)(&At[sk][sq * 4]) = av;
    {
      const float* wrow = W + (size_t)(ks + sk) * ldw + col0;
      float w[4];
      float rowmask = 1.f;
      if (MODE == 2) rowmask = (float)adj[(size_t)(ks + sk) * NN + (NN - 1)];
#pragma unroll
      for (int e = 0; e < 4; ++e) {
        int cl = c0 + sq * 4 + e;
        float wv = 0.f;
        if (cl < ncols) {
          wv = wrow[cl];
          if (MODE == 1) wv *= (float)adj[(size_t)(ks + sk) * NN + col0 + cl];
          if (MODE == 2) wv *= rowmask;
        }
        w[e] = wv;
      }
      *(float4*)(&Wt[sk][sq * 4]) = make_float4(w[0], w[1], w[2], w[3]);
    }
    __syncthreads();
#pragma unroll
    for (int kk = 0; kk < 16; ++kk) {
      float a4[4], w4[4];
#pragma unroll
      for (int e = 0; e < 4; ++e) a4[e] = At[kk][tb * 4 + e];
#pragma unroll
      for (int e = 0; e < 4; ++e) w4[e] = Wt[kk][tc * 4 + e];
#pragma unroll
      for (int i = 0; i < 4; ++i)
#pragma unroll
        for (int j = 0; j < 4; ++j) acc[i][j] = fmaf(a4[i], w4[j], acc[i][j]);
    }
    __syncthreads();
  }

#pragma unroll
  for (int j = 0; j < 4; ++j) {
    int cl = c0 + tc * 4 + j;
    if (cl < ncols) {
      float* dst = accT + (size_t)(col0 + cl) * 64 + tb * 4;
#pragma unroll
      for (int i = 0; i < 4; ++i) atomicAdd(dst + i, acc[i][j]);
    }
  }
}

// ---------------- init finish ----------------
__global__ void init_finish(const float* __restrict__ out0accT, const float* __restrict__ b0,
                            const unsigned char* __restrict__ adjN, const int* __restrict__ nl_idx,
                            float* __restrict__ curT) {
  int g = blockIdx.x * blockDim.x + threadIdx.x;
  int n = g >> 6;
  float v = out0accT[g] + b0[n];
  v = apply_nl(nl_idx[0], v);
  curT[g] = adjN[n] ? v : 0.f;
}

// ---------------- fused solve v8: R12 structure + prep-only-needed nl ----------------
__global__ __launch_bounds__(256, 1) void fused_solve(
    const float* __restrict__ wpack, const float* __restrict__ Wmid,
    const unsigned char* __restrict__ adjN, const int* __restrict__ nlidx,
    const float* __restrict__ bmid, const float* __restrict__ Cbase,
    float* __restrict__ curT, float* __restrict__ deltaG, int* chunkDone)
{
  __shared__ __align__(16) unsigned char smem[132096];
  float (*wmS)[TBLK]     = (float(*)[TBLK])(smem);           // 64 KiB triangle
  float (*wpr)[TBLK]     = (float(*)[TBLK])(smem + 65536);   // 64 KiB cross-pair weights
  float (*deltaFull)[64] = (float(*)[64])(smem + 65536);     // 32 KiB (aliases wpr post-apply)
  int* idS               = (int*)(smem + 131072);            // 512 B
  int* sfl               = (int*)(smem + 131584);

  const int bi = blockIdx.x;
  const int n0 = 1 + bi * TBLK;
  int size = NN - 1 - n0;
  if (size > TBLK) size = TBLK;
  const int tid = threadIdx.x;
  const int wv = tid >> 6;
  const int b = tid & 63;
  const int qbase = wv * 32;

  // ---- stage triangle (two halves to limit transient regs) ----
  {
    const float4* src = (const float4*)(wpack + (size_t)bi * TBLK * TBLK);
    float4 s0[8];
#pragma unroll
    for (int it = 0; it < 8; ++it) s0[it] = src[it * 256 + tid];
#pragma unroll
    for (int it = 0; it < 8; ++it) ((float4*)&wmS[0][0])[it * 256 + tid] = s0[it];
#pragma unroll
    for (int it = 0; it < 8; ++it) s0[it] = src[(8 + it) * 256 + tid];
#pragma unroll
    for (int it = 0; it < 8; ++it) ((float4*)&wmS[0][0])[(8 + it) * 256 + tid] = s0[it];
  }
  if (tid < TBLK) idS[tid] = (tid < size) ? nlidx[n0 + tid] : 3;

  // ---- val (Cbase + bias) and iv (init state) in registers ----
  float val[32], iv[32];
#pragma unroll
  for (int l = 0; l < 32; ++l) {
    int q = qbase + l, n = n0 + q;
    bool ok = q < size;
    val[l] = ok ? (Cbase[(size_t)n * 64 + b] + bmid[n]) : 0.f;
    iv[l] = ok ? curT[(size_t)n * 64 + b] : 0.f;
  }
  __syncthreads();

  // ---- incremental applies, chunk-granular (overlap producer solves) ----
#pragma unroll 1
  for (int p = 0; p < bi; ++p) {
    // prestage masked cross-weights for pair (p -> bi)
    {
      const size_t rowg0 = (size_t)(1 + p * TBLK);
#pragma unroll 1
      for (int it = 0; it < 16; ++it) {
        int idx = it * 256 + tid;
        int r = idx >> 5, c4 = (idx & 31) * 4;
        const float* wrow = Wmid + (rowg0 + r) * NN + n0;
        const unsigned char* arow = adjN + (rowg0 + r) * NN + n0;
        float w[4];
#pragma unroll
        for (int e = 0; e < 4; ++e) {
          int cl = c4 + e;
          w[e] = (cl < size && arow[cl]) ? wrow[cl] : 0.f;
        }
        *(float4*)(&wpr[r][c4]) = make_float4(w[0], w[1], w[2], w[3]);
      }
    }
    __syncthreads();  // wpr staged

#pragma unroll 1
    for (int c2 = 0; c2 < 4; ++c2) {
      // wait for producer p's chunk c2
      {
        int done = 0, cnt = 0;
        while (!done && cnt < 4000000) {
          if (tid == 0) *sfl = atomicAdd(&chunkDone[p * 4 + c2], 0);
          __syncthreads();
          done = *sfl;
          __syncthreads();
          ++cnt;
          if (!done) __builtin_amdgcn_s_sleep(2);
        }
      }
      __threadfence();  // acquire producer's chunk deltas
      // apply rank-32: rows c2*32 .. c2*32+31 (full unroll; compiler pipelines)
      const float* dsrc = deltaG + ((size_t)p * TBLK + c2 * 32) * 64 + b;
#pragma unroll
      for (int r = 0; r < 32; ++r) {
        const float d = dsrc[(size_t)r * 64];
        const float4* wr = (const float4*)(&wpr[c2 * 32 + r][qbase]);
#pragma unroll
        for (int g2 = 0; g2 < 8; ++g2) {
          float4 w4 = wr[g2];
          val[g2 * 4 + 0] = fmaf(d, w4.x, val[g2 * 4 + 0]);
          val[g2 * 4 + 1] = fmaf(d, w4.y, val[g2 * 4 + 1]);
          val[g2 * 4 + 2] = fmaf(d, w4.z, val[g2 * 4 + 2]);
          val[g2 * 4 + 3] = fmaf(d, w4.w, val[g2 * 4 + 3]);
        }
      }
    }
    __syncthreads();  // before next p overwrites wpr
  }

  // ---- 4-phase chunked triangular solve; Phase A sub-chunked 8-wide ----
#pragma unroll 1
  for (int c = 0; c < 4; ++c) {
    if (wv == c) {
      const int jbase = c * 32;
      int idv = idS[jbase];
      float pre = nl_prep(idv, val[0]);
#pragma unroll
      for (int s = 0; s < 4; ++s) {
        // preload in-sub 8x8 triangle rows into regs
        float4 tw[16];
#pragma unroll
        for (int m = 0; m < 8; ++m) {
          const float4* tr = (const float4*)(&wmS[jbase + s * 8 + m][qbase + s * 8]);
          tw[m * 2] = tr[0];
          tw[m * 2 + 1] = tr[1];
        }
        float ds[8];
        // ---- micro-solve: 8 serial steps ----
#pragma unroll
        for (int m = 0; m < 8; ++m) {
          const int jj = s * 8 + m;
          const int j = jbase + jj;
          float nv = nl_fin(idv, val[jj], pre);
          float delta = (j < size) ? (nv - iv[jj]) : 0.f;
          ds[m] = delta;
          deltaFull[j][b] = delta;
          if (jj < 31) idv = idS[jbase + jj + 1];
          if (m < 7) {
            val[s * 8 + m + 1] = fmaf(delta, TWEL(tw, m, m + 1), val[s * 8 + m + 1]);
            pre = nl_prep(idv, val[s * 8 + m + 1]);
#pragma unroll
            for (int l = m + 2; l < 8; ++l)
              val[s * 8 + l] = fmaf(delta, TWEL(tw, m, l), val[s * 8 + l]);
          }
        }
        // ---- batched rank-8 update of later subs (first group -> prep) ----
        if (s < 3) {
#pragma unroll
          for (int lg = (s + 1) * 2; lg < 8; ++lg) {
#pragma unroll
            for (int m = 0; m < 8; ++m) {
              const float4 w4 = *(const float4*)(&wmS[jbase + s * 8 + m][qbase + lg * 4]);
              val[lg * 4 + 0] = fmaf(ds[m], w4.x, val[lg * 4 + 0]);
              val[lg * 4 + 1] = fmaf(ds[m], w4.y, val[lg * 4 + 1]);
              val[lg * 4 + 2] = fmaf(ds[m], w4.z, val[lg * 4 + 2]);
              val[lg * 4 + 3] = fmaf(ds[m], w4.w, val[lg * 4 + 3]);
            }
            if (lg == (s + 1) * 2)
              pre = nl_prep(idv, val[(s + 1) * 8]);
          }
        }
      }
    }
    __syncthreads();  // deltas of chunk c visible in LDS
    if (wv == c) {
      // ---- wave c (idle in Phase B): export chunk deltas + flag ----
      const float4* sdel = (const float4*)(&deltaFull[c * 32][0]);  // 512 float4
      float4* dstD = (float4*)(deltaG + ((size_t)bi * TBLK + c * 32) * 64);
#pragma unroll
      for (int it = 0; it < 8; ++it) dstD[it * 64 + b] = sdel[it * 64 + b];
      __threadfence();  // wave-level vmcnt drain + release
      if (b == 0) atomicExch(&chunkDone[bi * 4 + c], 1);
    } else if (wv > c) {
      // ---- Phase B: rank-32 update of own slots (full unroll) ----
#pragma unroll
      for (int jj = 0; jj < 32; ++jj) {
        const int j = c * 32 + jj;
        const float delta = deltaFull[j][b];
        const float4* wr = (const float4*)(&wmS[j][qbase]);
#pragma unroll
        for (int g2 = 0; g2 < 8; ++g2) {
          float4 w4 = wr[g2];
          val[g2 * 4 + 0] = fmaf(delta, w4.x, val[g2 * 4 + 0]);
          val[g2 * 4 + 1] = fmaf(delta, w4.y, val[g2 * 4 + 1]);
          val[g2 * 4 + 2] = fmaf(delta, w4.z, val[g2 * 4 + 2]);
          val[g2 * 4 + 3] = fmaf(delta, w4.w, val[g2 * 4 + 3]);
        }
      }
    }
    __syncthreads();
  }

  // ---- final: curT += deltas (curT held iv) ----
  {
    const float4* sdel = (const float4*)&deltaFull[0][0];
    float4* dstC = (float4*)(curT + (size_t)n0 * 64);
#pragma unroll
    for (int it = 0; it < 8; ++it) {
      int v = it * 256 + tid;
      int r = v >> 4;
      if (r < size) {
        float4 d = sdel[v];
        float4 cc = dstC[v];
        dstC[v] = make_float4(cc.x + d.x, cc.y + d.y, cc.z + d.z, cc.w + d.w);
      }
    }
  }
}

// ---------------- final finish ----------------
__global__ void final_finish(const float* __restrict__ outaccT, const float* __restrict__ bout,
                             const int* __restrict__ nlidx, float* __restrict__ out) {
  int g = blockIdx.x * blockDim.x + threadIdx.x;
  int c = g >> 6, b = g & 63;
  float v = outaccT[g] + bout[c];
  v = apply_nl(nlidx[NN - 1], v);
  out[(size_t)b * DOUT + c] = v;
}

// ---------------- state transpose ----------------
__global__ __launch_bounds__(256) void transpose_state(const float* __restrict__ curT,
                                                       float* __restrict__ stateOut) {
  __shared__ float tile[64][65];
  int n0 = blockIdx.x * 64;
  for (int r = 0; r < 16; ++r) {
    int e = r * 256 + threadIdx.x;
    tile[e >> 6][e & 63] = curT[(size_t)(n0 + (e >> 6)) * 64 + (e & 63)];
  }
  __syncthreads();
  for (int r = 0; r < 16; ++r) {
    int e = r * 256 + threadIdx.x;
    int bb = e >> 6, nn2 = e & 63;
    stateOut[(size_t)bb * NN + n0 + nn2] = tile[nn2][bb];
  }
}

extern "C" void kernel_launch(void* const* d_in, const int* in_sizes, int n_in,
                              void* d_out, int out_size, void* d_ws, size_t ws_size,
                              hipStream_t stream) {
  const float* X = (const float*)d_in[0];
  const unsigned char* adj = (const unsigned char*)d_in[1];
  const int* nl_idx = (const int*)d_in[2];
  const float* W0 = (const float*)d_in[3];
  const float* b0 = (const float*)d_in[4];
  const float* W_mid = (const float*)d_in[5];
  const float* b_mid = (const float*)d_in[6];
  const float* W_out = (const float*)d_in[7];
  const float* b_out = (const float*)d_in[8];
  float* out = (float*)d_out;
  float* stateOut = out + BN * DOUT;

  char* ws = (char*)d_ws;
  unsigned char* adjN = (unsigned char*)(ws + 0);       // 4 MiB
  int* flags = (int*)(ws + 4194304);                    // 512 B: [0..1]=detect, [8..71]=chunkDone
  float* XT = (float*)(ws + 4194816);                   // 256 KiB
  float* curT = (float*)(ws + 4456960);                 // 512 KiB
  float* Cbase = (float*)(ws + 4981248);                // 512 KiB (read-only after GEMM)
  float* out0accT = (float*)(ws + 5505536);             // 512 KiB
  float* outaccT = (float*)(ws + 6029824);              // 128 KiB
  float* wpack = (float*)(ws + 6160896);                // 1 MiB
  float* deltaG = (float*)(ws + 7209472);               // 512 KiB -> end 7733760
  int* chunkDone = flags + 8;

  hipMemsetAsync(flags, 0, 512, stream);
  hipMemsetAsync(Cbase, 0, 524288 + 524288 + 131072, stream);

  detect_adj<<<64, 256, 0, stream>>>((const unsigned int*)adj, flags);
  normalize_adj<<<16384, 256, 0, stream>>>(adj, flags, adjN);
  transpose_x<<<256, 256, 0, stream>>>(X, XT);
  pack_wmid<<<256, 256, 0, stream>>>(W_mid, adjN, wpack);

  gemm_partial<0><<<128, 256, 0, stream>>>(XT, W0, adjN, out0accT, NN, 0, NN, 256, 32);
  init_finish<<<512, 256, 0, stream>>>(out0accT, b0, adjN, nl_idx, curT);

  // Cbase: state_0 @ (W_mid * adj) for ALL columns (read-only afterwards)
  gemm_partial<1><<<256, 256, 0, stream>>>(curT, W_mid, adjN, Cbase, NN, 0, NN, 256, 32);

  // entire sequential middle: 16 self-applying solver WGs, per-chunk pipelined
  fused_solve<<<NBLK, 256, 0, stream>>>(wpack, W_mid, adjN, nl_idx, b_mid, Cbase,
                                        curT, deltaG, chunkDone);

  gemm_partial<2><<<64, 256, 0, stream>>>(curT, W_out, adjN, outaccT, DOUT, 0, DOUT, 256, 8);
  final_finish<<<128, 256, 0, stream>>>(outaccT, b_out, nl_idx, out);
  transpose_state<<<32, 256, 0, stream>>>(curT, stateOut);
}

// Round 16
// 731.867 us; speedup vs baseline: 1.5968x; 1.0139x over previous
//
#include <hip/hip_runtime.h>
#include <math.h>

#define BN 64
#define KIN 1024
#define DOUT 512
#define NN 2048
#define TBLK 128
#define NBLK 16

__device__ __forceinline__ float softplus_f(float x) {
  float e = __expf(-fabsf(x));
  return fmaxf(x, 0.f) + __logf(1.f + e);
}
__device__ __forceinline__ float apply_nl(int id, float v) {
  switch (id) {
    case 0: return fmaxf(v, 0.f);
    case 1: { float e = __expf(2.f * v); return fmaf(-2.f, __builtin_amdgcn_rcpf(e + 1.f), 1.f); }
    case 2: return v >= 0.f ? v : 0.01f * v;
    case 3: return v;
    case 4: return __sinf(v);
    case 5: return softplus_f(v);
    default: return v - softplus_f(v);  // -softplus(-v)
  }
}

// Prep-only-what's-needed nl (serial-solver path).
__device__ __forceinline__ float nl_prep(int id, float v) {
  id = __builtin_amdgcn_readfirstlane(id);
  if (id == 0 || id == 2 || id == 3) return 0.f;  // cheap ids: no prep needed
  if (id == 4) return __sinf(v);
  if (id == 1) {
    float e = __expf(2.f * v);
    return fmaf(-2.f, __builtin_amdgcn_rcpf(e + 1.f), 1.f);
  }
  float sp = softplus_f(v);
  return (id == 5) ? sp : v - sp;  // 5: softplus, 6: softminus
}
__device__ __forceinline__ float nl_fin(int id, float v, float pre) {
  float mx = fmaxf(v, 0.f);
  float r = (id == 2) ? fmaf(fminf(v, 0.f), 0.01f, mx) : pre;
  r = (id == 0) ? mx : r;
  r = (id == 3) ? v : r;
  return r;
}

// element (m-row, l-col) of per-sub triangle regs tw[16] (float4 pairs per row)
#define TWEL(tw, m, l) (((l) & 3) == 0 ? tw[(m)*2 + ((l) >> 2)].x : \
                        ((l) & 3) == 1 ? tw[(m)*2 + ((l) >> 2)].y : \
                        ((l) & 3) == 2 ? tw[(m)*2 + ((l) >> 2)].z : tw[(m)*2 + ((l) >> 2)].w)

// ---------------- adj dtype detection (parallel) ----------------
__global__ void detect_adj(const unsigned int* __restrict__ a, int* __restrict__ flags) {
  int idx = blockIdx.x * 256 + threadIdx.x;  // 16384 dwords = first 64 KiB
  unsigned int v = a[idx];
  bool bad = ((v & 0xFFu) > 1u) || (((v >> 8) & 0xFFu) > 1u) ||
             (((v >> 16) & 0xFFu) > 1u) || ((v >> 24) > 1u);
  bool off = (v & 0xFFFFFF00u) != 0u;
  if (__any(bad) && (threadIdx.x & 63) == 0) atomicOr(&flags[0], 1);
  if (__any(off) && (threadIdx.x & 63) == 0) atomicOr(&flags[1], 1);
}

__global__ void normalize_adj(const unsigned char* __restrict__ a,
                              const int* __restrict__ flags,
                              unsigned char* __restrict__ out) {
  size_t i = (size_t)blockIdx.x * blockDim.x + threadIdx.x;
  int mode = flags[0] ? 2 : (flags[1] ? 1 : 0);
  unsigned char r;
  if (mode == 1)      r = (a[i] != 0);
  else if (mode == 0) r = (((const int*)a)[i] != 0);
  else                r = (((const float*)a)[i] != 0.f);
  out[i] = r;
}

// ---------------- X transpose ----------------
__global__ void transpose_x(const float* __restrict__ X, float* __restrict__ XT) {
  int g = blockIdx.x * blockDim.x + threadIdx.x;
  int k = g >> 6, b = g & 63;
  XT[g] = X[(size_t)b * KIN + k];
}

// ---------------- pack aligned in-block triangles ----------------
__global__ __launch_bounds__(256) void pack_wmid(const float* __restrict__ Wmid,
                                                 const unsigned char* __restrict__ adjN,
                                                 float* __restrict__ wpack) {
  int g = blockIdx.x * 256 + threadIdx.x;  // 65536 float4s
  int i = g >> 12;
  int rem = g & 4095;
  int j = rem >> 5;
  int q4 = (rem & 31) * 4;
  int n0 = 1 + i * TBLK;
  int size = NN - 1 - n0;
  if (size > TBLK) size = TBLK;
  float w[4];
#pragma unroll
  for (int e = 0; e < 4; ++e) {
    int q = q4 + e;
    float v = 0.f;
    if (q > j && j < size && q < size) {
      size_t idx = (size_t)(n0 + j) * NN + (size_t)(n0 + q);
      v = Wmid[idx] * (float)adjN[idx];
    }
    w[e] = v;
  }
  *(float4*)(wpack + (size_t)g * 4) = make_float4(w[0], w[1], w[2], w[3]);
}

// ---------------- unified partial GEMM ----------------
template <int MODE>
__global__ __launch_bounds__(256) void gemm_partial(
    const float* __restrict__ AT, const float* __restrict__ W,
    const unsigned char* __restrict__ adj, float* __restrict__ accT,
    int ldw, int col0, int ncols, int kPerChunk, int nColTiles)
{
  const int ct = blockIdx.x % nColTiles;
  const int kc = blockIdx.x / nColTiles;
  const int c0 = ct * 64;
  const int k0 = kc * kPerChunk;
  const int t = threadIdx.x;
  const int tb = t >> 4;
  const int tc = t & 15;

  __shared__ __align__(16) float At[16][64];
  __shared__ __align__(16) float Wt[16][64];

  float acc[4][4] = {};
  const int sk = t >> 4;
  const int sq = t & 15;

  for (int ks = k0; ks < k0 + kPerChunk; ks += 16) {
    const float4 av = *(const float4*)(AT + (size_t)(ks + sk) * 64 + sq * 4);
    *(float4*)(&At[sk][sq * 4]) = av;
    {
      const float* wrow = W + (size_t)(ks + sk) * ldw + col0;
      float w[4];
      float rowmask = 1.f;
      if (MODE == 2) rowmask = (float)adj[(size_t)(ks + sk) * NN + (NN - 1)];
#pragma unroll
      for (int e = 0; e < 4; ++e) {
        int cl = c0 + sq * 4 + e;
        float wv = 0.f;
        if (cl < ncols) {
          wv = wrow[cl];
          if (MODE == 1) wv *= (float)adj[(size_t)(ks + sk) * NN + col0 + cl];
          if (MODE == 2) wv *= rowmask;
        }
        w[e] = wv;
      }
      *(float4*)(&Wt[sk][sq * 4]) = make_float4(w[0], w[1], w[2], w[3]);
    }
    __syncthreads();
#pragma unroll
    for (int kk = 0; kk < 16; ++kk) {
      float a4[4], w4[4];
#pragma unroll
      for (int e = 0; e < 4; ++e) a4[e] = At[kk][tb * 4 + e];
#pragma unroll
      for (int e = 0; e < 4; ++e) w4[e] = Wt[kk][tc * 4 + e];
#pragma unroll
      for (int i = 0; i < 4; ++i)
#pragma unroll
        for (int j = 0; j < 4; ++j) acc[i][j] = fmaf(a4[i], w4[j], acc[i][j]);
    }
    __syncthreads();
  }

#pragma unroll
  for (int j = 0; j < 4; ++j) {
    int cl = c0 + tc * 4 + j;
    if (cl < ncols) {
      float* dst = accT + (size_t)(col0 + cl) * 64 + tb * 4;
#pragma unroll
      for (int i = 0; i < 4; ++i) atomicAdd(dst + i, acc[i][j]);
    }
  }
}

// ---------------- init finish ----------------
__global__ void init_finish(const float* __restrict__ out0accT, const float* __restrict__ b0,
                            const unsigned char* __restrict__ adjN, const int* __restrict__ nl_idx,
                            float* __restrict__ curT) {
  int g = blockIdx.x * blockDim.x + threadIdx.x;
  int n = g >> 6;
  float v = out0accT[g] + b0[n];
  v = apply_nl(nl_idx[0], v);
  curT[g] = adjN[n] ? v : 0.f;
}

// ---------------- fused solve v9: v8 + barrier-free per-wave chunk polling ----------
__global__ __launch_bounds__(256, 1) void fused_solve(
    const float* __restrict__ wpack, const float* __restrict__ Wmid,
    const unsigned char* __restrict__ adjN, const int* __restrict__ nlidx,
    const float* __restrict__ bmid, const float* __restrict__ Cbase,
    float* __restrict__ curT, float* __restrict__ deltaG, int* chunkDone)
{
  __shared__ __align__(16) unsigned char smem[132096];
  float (*wmS)[TBLK]     = (float(*)[TBLK])(smem);           // 64 KiB triangle
  float (*wpr)[TBLK]     = (float(*)[TBLK])(smem + 65536);   // 64 KiB cross-pair weights
  float (*deltaFull)[64] = (float(*)[64])(smem + 65536);     // 32 KiB (aliases wpr post-apply)
  int* idS               = (int*)(smem + 131072);            // 512 B

  const int bi = blockIdx.x;
  const int n0 = 1 + bi * TBLK;
  int size = NN - 1 - n0;
  if (size > TBLK) size = TBLK;
  const int tid = threadIdx.x;
  const int wv = tid >> 6;
  const int b = tid & 63;
  const int qbase = wv * 32;

  // ---- stage triangle (two halves to limit transient regs) ----
  {
    const float4* src = (const float4*)(wpack + (size_t)bi * TBLK * TBLK);
    float4 s0[8];
#pragma unroll
    for (int it = 0; it < 8; ++it) s0[it] = src[it * 256 + tid];
#pragma unroll
    for (int it = 0; it < 8; ++it) ((float4*)&wmS[0][0])[it * 256 + tid] = s0[it];
#pragma unroll
    for (int it = 0; it < 8; ++it) s0[it] = src[(8 + it) * 256 + tid];
#pragma unroll
    for (int it = 0; it < 8; ++it) ((float4*)&wmS[0][0])[(8 + it) * 256 + tid] = s0[it];
  }
  if (tid < TBLK) idS[tid] = (tid < size) ? nlidx[n0 + tid] : 3;

  // ---- val (Cbase + bias) and iv (init state) in registers ----
  float val[32], iv[32];
#pragma unroll
  for (int l = 0; l < 32; ++l) {
    int q = qbase + l, n = n0 + q;
    bool ok = q < size;
    val[l] = ok ? (Cbase[(size_t)n * 64 + b] + bmid[n]) : 0.f;
    iv[l] = ok ? curT[(size_t)n * 64 + b] : 0.f;
  }
  __syncthreads();

  // ---- incremental applies, chunk-granular; per-wave barrier-free polling ----
#pragma unroll 1
  for (int p = 0; p < bi; ++p) {
    // prestage masked cross-weights for pair (p -> bi)
    {
      const size_t rowg0 = (size_t)(1 + p * TBLK);
#pragma unroll 1
      for (int it = 0; it < 16; ++it) {
        int idx = it * 256 + tid;
        int r = idx >> 5, c4 = (idx & 31) * 4;
        const float* wrow = Wmid + (rowg0 + r) * NN + n0;
        const unsigned char* arow = adjN + (rowg0 + r) * NN + n0;
        float w[4];
#pragma unroll
        for (int e = 0; e < 4; ++e) {
          int cl = c4 + e;
          w[e] = (cl < size && arow[cl]) ? wrow[cl] : 0.f;
        }
        *(float4*)(&wpr[r][c4]) = make_float4(w[0], w[1], w[2], w[3]);
      }
    }
    __syncthreads();  // wpr staged (all waves see it)

#pragma unroll 1
    for (int c2 = 0; c2 < 4; ++c2) {
      // per-wave wait: lane 0 polls, readfirstlane broadcasts; no block barriers
      {
        int done = 0, cnt = 0;
        while (!done && cnt < 4000000) {
          int f = 0;
          if (b == 0) f = atomicAdd(&chunkDone[p * 4 + c2], 0);
          f = __builtin_amdgcn_readfirstlane(f);
          done = f;
          if (!done) {
            __builtin_amdgcn_s_sleep(1);
            ++cnt;
          }
        }
      }
      __threadfence();  // acquire producer's chunk deltas (per-wave)
      // apply rank-32: rows c2*32 .. c2*32+31 (full unroll; compiler pipelines)
      const float* dsrc = deltaG + ((size_t)p * TBLK + c2 * 32) * 64 + b;
#pragma unroll
      for (int r = 0; r < 32; ++r) {
        const float d = dsrc[(size_t)r * 64];
        const float4* wr = (const float4*)(&wpr[c2 * 32 + r][qbase]);
#pragma unroll
        for (int g2 = 0; g2 < 8; ++g2) {
          float4 w4 = wr[g2];
          val[g2 * 4 + 0] = fmaf(d, w4.x, val[g2 * 4 + 0]);
          val[g2 * 4 + 1] = fmaf(d, w4.y, val[g2 * 4 + 1]);
          val[g2 * 4 + 2] = fmaf(d, w4.z, val[g2 * 4 + 2]);
          val[g2 * 4 + 3] = fmaf(d, w4.w, val[g2 * 4 + 3]);
        }
      }
    }
    __syncthreads();  // before next p overwrites wpr
  }

  // ---- 4-phase chunked triangular solve; Phase A sub-chunked 8-wide ----
#pragma unroll 1
  for (int c = 0; c < 4; ++c) {
    if (wv == c) {
      const int jbase = c * 32;
      int idv = idS[jbase];
      float pre = nl_prep(idv, val[0]);
#pragma unroll
      for (int s = 0; s < 4; ++s) {
        // preload in-sub 8x8 triangle rows into regs
        float4 tw[16];
#pragma unroll
        for (int m = 0; m < 8; ++m) {
          const float4* tr = (const float4*)(&wmS[jbase + s * 8 + m][qbase + s * 8]);
          tw[m * 2] = tr[0];
          tw[m * 2 + 1] = tr[1];
        }
        float ds[8];
        // ---- micro-solve: 8 serial steps ----
#pragma unroll
        for (int m = 0; m < 8; ++m) {
          const int jj = s * 8 + m;
          const int j = jbase + jj;
          float nv = nl_fin(idv, val[jj], pre);
          float delta = (j < size) ? (nv - iv[jj]) : 0.f;
          ds[m] = delta;
          deltaFull[j][b] = delta;
          if (jj < 31) idv = idS[jbase + jj + 1];
          if (m < 7) {
            val[s * 8 + m + 1] = fmaf(delta, TWEL(tw, m, m + 1), val[s * 8 + m + 1]);
            pre = nl_prep(idv, val[s * 8 + m + 1]);
#pragma unroll
            for (int l = m + 2; l < 8; ++l)
              val[s * 8 + l] = fmaf(delta, TWEL(tw, m, l), val[s * 8 + l]);
          }
        }
        // ---- batched rank-8 update of later subs (first group -> prep) ----
        if (s < 3) {
#pragma unroll
          for (int lg = (s + 1) * 2; lg < 8; ++lg) {
#pragma unroll
            for (int m = 0; m < 8; ++m) {
              const float4 w4 = *(const float4*)(&wmS[jbase + s * 8 + m][qbase + lg * 4]);
              val[lg * 4 + 0] = fmaf(ds[m], w4.x, val[lg * 4 + 0]);
              val[lg * 4 + 1] = fmaf(ds[m], w4.y, val[lg * 4 + 1]);
              val[lg * 4 + 2] = fmaf(ds[m], w4.z, val[lg * 4 + 2]);
              val[lg * 4 + 3] = fmaf(ds[m], w4.w, val[lg * 4 + 3]);
            }
            if (lg == (s + 1) * 2)
              pre = nl_prep(idv, val[(s + 1) * 8]);
          }
        }
      }
    }
    __syncthreads();  // deltas of chunk c visible in LDS
    if (wv == c) {
      // ---- wave c (idle in Phase B): export chunk deltas + flag ----
      const float4* sdel = (const float4*)(&deltaFull[c * 32][0]);  // 512 float4
      float4* dstD = (float4*)(deltaG + ((size_t)bi * TBLK + c * 32) * 64);
#pragma unroll
      for (int it = 0; it < 8; ++it) dstD[it * 64 + b] = sdel[it * 64 + b];
      __threadfence();  // wave-level vmcnt drain + release
      if (b == 0) atomicExch(&chunkDone[bi * 4 + c], 1);
    } else if (wv > c) {
      // ---- Phase B: rank-32 update of own slots (full unroll) ----
#pragma unroll
      for (int jj = 0; jj < 32; ++jj) {
        const int j = c * 32 + jj;
        const float delta = deltaFull[j][b];
        const float4* wr = (const float4*)(&wmS[j][qbase]);
#pragma unroll
        for (int g2 = 0; g2 < 8; ++g2) {
          float4 w4 = wr[g2];
          val[g2 * 4 + 0] = fmaf(delta, w4.x, val[g2 * 4 + 0]);
          val[g2 * 4 + 1] = fmaf(delta, w4.y, val[g2 * 4 + 1]);
          val[g2 * 4 + 2] = fmaf(delta, w4.z, val[g2 * 4 + 2]);
          val[g2 * 4 + 3] = fmaf(delta, w4.w, val[g2 * 4 + 3]);
        }
      }
    }
    __syncthreads();
  }

  // ---- final: curT += deltas (curT held iv) ----
  {
    const float4* sdel = (const float4*)&deltaFull[0][0];
    float4* dstC = (float4*)(curT + (size_t)n0 * 64);
#pragma unroll
    for (int it = 0; it < 8; ++it) {
      int v = it * 256 + tid;
      int r = v >> 4;
      if (r < size) {
        float4 d = sdel[v];
        float4 cc = dstC[v];
        dstC[v] = make_float4(cc.x + d.x, cc.y + d.y, cc.z + d.z, cc.w + d.w);
      }
    }
  }
}

// ---------------- final finish ----------------
__global__ void final_finish(const float* __restrict__ outaccT, const float* __restrict__ bout,
                             const int* __restrict__ nlidx, float* __restrict__ out) {
  int g = blockIdx.x * blockDim.x + threadIdx.x;
  int c = g >> 6, b = g & 63;
  float v = outaccT[g] + bout[c];
  v = apply_nl(nlidx[NN - 1], v);
  out[(size_t)b * DOUT + c] = v;
}

// ---------------- state transpose ----------------
__global__ __launch_bounds__(256) void transpose_state(const float* __restrict__ curT,
                                                       float* __restrict__ stateOut) {
  __shared__ float tile[64][65];
  int n0 = blockIdx.x * 64;
  for (int r = 0; r < 16; ++r) {
    int e = r * 256 + threadIdx.x;
    tile[e >> 6][e & 63] = curT[(size_t)(n0 + (e >> 6)) * 64 + (e & 63)];
  }
  __syncthreads();
  for (int r = 0; r < 16; ++r) {
    int e = r * 256 + threadIdx.x;
    int bb = e >> 6, nn2 = e & 63;
    stateOut[(size_t)bb * NN + n0 + nn2] = tile[nn2][bb];
  }
}

extern "C" void kernel_launch(void* const* d_in, const int* in_sizes, int n_in,
                              void* d_out, int out_size, void* d_ws, size_t ws_size,
                              hipStream_t stream) {
  const float* X = (const float*)d_in[0];
  const unsigned char* adj = (const unsigned char*)d_in[1];
  const int* nl_idx = (const int*)d_in[2];
  const float* W0 = (const float*)d_in[3];
  const float* b0 = (const float*)d_in[4];
  const float* W_mid = (const float*)d_in[5];
  const float* b_mid = (const float*)d_in[6];
  const float* W_out = (const float*)d_in[7];
  const float* b_out = (const float*)d_in[8];
  float* out = (float*)d_out;
  float* stateOut = out + BN * DOUT;

  char* ws = (char*)d_ws;
  unsigned char* adjN = (unsigned char*)(ws + 0);       // 4 MiB
  int* flags = (int*)(ws + 4194304);                    // 512 B: [0..1]=detect, [8..71]=chunkDone
  float* XT = (float*)(ws + 4194816);                   // 256 KiB
  float* curT = (float*)(ws + 4456960);                 // 512 KiB
  float* Cbase = (float*)(ws + 4981248);                // 512 KiB (read-only after GEMM)
  float* out0accT = (float*)(ws + 5505536);             // 512 KiB
  float* outaccT = (float*)(ws + 6029824);              // 128 KiB
  float* wpack = (float*)(ws + 6160896);                // 1 MiB
  float* deltaG = (float*)(ws + 7209472);               // 512 KiB -> end 7733760
  int* chunkDone = flags + 8;

  hipMemsetAsync(flags, 0, 512, stream);
  hipMemsetAsync(Cbase, 0, 524288 + 524288 + 131072, stream);

  detect_adj<<<64, 256, 0, stream>>>((const unsigned int*)adj, flags);
  normalize_adj<<<16384, 256, 0, stream>>>(adj, flags, adjN);
  transpose_x<<<256, 256, 0, stream>>>(X, XT);
  pack_wmid<<<256, 256, 0, stream>>>(W_mid, adjN, wpack);

  gemm_partial<0><<<128, 256, 0, stream>>>(XT, W0, adjN, out0accT, NN, 0, NN, 256, 32);
  init_finish<<<512, 256, 0, stream>>>(out0accT, b0, adjN, nl_idx, curT);

  // Cbase: state_0 @ (W_mid * adj) for ALL columns (read-only afterwards)
  gemm_partial<1><<<256, 256, 0, stream>>>(curT, W_mid, adjN, Cbase, NN, 0, NN, 256, 32);

  // entire sequential middle: 16 self-applying solver WGs, per-chunk pipelined
  fused_solve<<<NBLK, 256, 0, stream>>>(wpack, W_mid, adjN, nl_idx, b_mid, Cbase,
                                        curT, deltaG, chunkDone);

  gemm_partial<2><<<64, 256, 0, stream>>>(curT, W_out, adjN, outaccT, DOUT, 0, DOUT, 256, 8);
  final_finish<<<128, 256, 0, stream>>>(outaccT, b_out, nl_idx, out);
  transpose_state<<<32, 256, 0, stream>>>(curT, stateOut);
}